// Round 2
// baseline (435.129 us; speedup 1.0000x reference)
//
#include <hip/hip_runtime.h>
#include <cstdint>
#include <cstddef>

#define M_DIM 4096
#define K_DIM 4096
#define N_DIM 8192

typedef int v4i __attribute__((ext_vector_type(4)));

__device__ __forceinline__ void load_lds16(const void* g, void* l) {
  __builtin_amdgcn_global_load_lds(
      (const __attribute__((address_space(1))) void*)g,
      (__attribute__((address_space(3))) void*)l,
      16, 0, 0);
}

__device__ __forceinline__ uint32_t pack4(int4 v) {
  return ((uint32_t)v.x & 0xFFu) | (((uint32_t)v.y & 0xFFu) << 8) |
         (((uint32_t)v.z & 0xFFu) << 16) | ((uint32_t)v.w << 24);
}

// ---------------------------------------------------------------------------
// A int32 [M][K] -> A8 int8 [M][K]. Each thread: 64B read -> 16B write.
// ---------------------------------------------------------------------------
__global__ __launch_bounds__(256) void pack_a_kernel(const int* __restrict__ A32,
                                                     uint8_t* __restrict__ A8) {
  const int n16 = (M_DIM * K_DIM) / 16;  // 16 elems per thread-iter
  const int stride = gridDim.x * 256;
  for (int i = blockIdx.x * 256 + threadIdx.x; i < n16; i += stride) {
    const int4* src = reinterpret_cast<const int4*>(A32) + (size_t)i * 4;
    int4 o;
    o.x = (int)pack4(src[0]);
    o.y = (int)pack4(src[1]);
    o.z = (int)pack4(src[2]);
    o.w = (int)pack4(src[3]);
    reinterpret_cast<int4*>(A8)[i] = o;
  }
}

// ---------------------------------------------------------------------------
// B int32 [K][N] -> Bt int8 [N][K]. 128x128 tiles through LDS (pitch 132:
// stage-1 dword writes conflict-free, stage-2 dword reads conflict-free).
// ---------------------------------------------------------------------------
#define TPITCH 132
__global__ __launch_bounds__(256) void pack_bt_kernel(const int* __restrict__ B32,
                                                      uint8_t* __restrict__ Bt) {
  __shared__ uint8_t tile[128 * TPITCH];
  const int t = threadIdx.x;
  const int n0 = blockIdx.x * 128;
  const int k0 = blockIdx.y * 128;

  // stage 1: read int32, pack to int8 rows tile[k][n]
#pragma unroll
  for (int c = 0; c < 16; ++c) {
    const int chunk = c * 256 + t;        // 0..4095, 4 int32 each
    const int row = chunk >> 5;           // k-row 0..127
    const int nc4 = (chunk & 31);         // n-dword 0..31
    const int4 v = *reinterpret_cast<const int4*>(
        B32 + (size_t)(k0 + row) * N_DIM + n0 + nc4 * 4);
    *reinterpret_cast<uint32_t*>(&tile[row * TPITCH + nc4 * 4]) = pack4(v);
  }
  __syncthreads();

  // stage 2: each thread transposes a 4(n) x 16(k) byte block via v_perm
  const int nb = (t & 31) << 2;   // n offset 0..124
  const int kc = (t >> 5) << 4;   // k offset 0..112
  uint32_t dw[16];
#pragma unroll
  for (int j = 0; j < 16; ++j)
    dw[j] = *reinterpret_cast<const uint32_t*>(&tile[(kc + j) * TPITCH + nb]);

#pragma unroll
  for (int np = 0; np < 4; ++np) {
    const uint32_t sel = (uint32_t)np | (((uint32_t)np + 4u) << 8);
    uint32_t o[4];
#pragma unroll
    for (int d = 0; d < 4; ++d) {
      const uint32_t p01 = __builtin_amdgcn_perm(dw[4 * d + 1], dw[4 * d + 0], sel);
      const uint32_t p23 = __builtin_amdgcn_perm(dw[4 * d + 3], dw[4 * d + 2], sel);
      o[d] = __builtin_amdgcn_perm(p23, p01, 0x05040100u);
    }
    const int4 v = make_int4((int)o[0], (int)o[1], (int)o[2], (int)o[3]);
    *reinterpret_cast<int4*>(Bt + (size_t)(n0 + nb + np) * K_DIM + k0 + kc) = v;
  }
}

// ---------------------------------------------------------------------------
// GEMM: C[m][n] = (float)(sum_k A[m][k]*B[k][n]) * scale[n]
// A8 [M][K] int8 row-major, Bt [N][K] int8 row-major (pre-transposed B).
// 128x128 tile, BK=64, 4 waves (2x2, 64x64 out each), mfma_i32_16x16x64_i8,
// global_load_lds(16B) direct staging, double-buffered LDS, 2-barrier loop.
// ---------------------------------------------------------------------------
__global__ __launch_bounds__(256) void gemm_i8_kernel(const uint8_t* __restrict__ A,
                                                      const uint8_t* __restrict__ Bt,
                                                      const float* __restrict__ scale,
                                                      float* __restrict__ C) {
  __shared__ uint8_t sA[2][128 * 64];
  __shared__ uint8_t sB[2][128 * 64];

  const int t = threadIdx.x;
  const int lane = t & 63;
  const int wave = t >> 6;
  const int wr = wave >> 1;   // wave row 0..1
  const int wc = wave & 1;    // wave col 0..1
  const int lr = lane & 15;   // fragment row/col within 16
  const int kh = lane >> 4;   // k-group 0..3 (16 bytes each)

  const int m0 = blockIdx.y * 128;
  const int n0 = blockIdx.x * 128;

  // staging: 512 chunks of 16B per tile (A and B each); this thread owns 2
  const int chunk0 = t;
  const int chunk1 = 256 + t;
  const int r0 = chunk0 >> 2, c0 = (chunk0 & 3) << 4;
  const int r1 = chunk1 >> 2, c1 = (chunk1 & 3) << 4;
  const uint8_t* a0 = A + (size_t)(m0 + r0) * K_DIM + c0;
  const uint8_t* a1 = A + (size_t)(m0 + r1) * K_DIM + c1;
  const uint8_t* b0 = Bt + (size_t)(n0 + r0) * K_DIM + c0;
  const uint8_t* b1 = Bt + (size_t)(n0 + r1) * K_DIM + c1;

  v4i acc[4][4];
#pragma unroll
  for (int i = 0; i < 4; ++i)
#pragma unroll
    for (int j = 0; j < 4; ++j)
      acc[i][j] = (v4i){0, 0, 0, 0};

  const int aoffBase = (wr * 64 + lr) * 64 + kh * 16;
  const int boffBase = (wc * 64 + lr) * 64 + kh * 16;

  // prologue: stage k-tile 0 into buffer 0
  load_lds16(a0, &sA[0][chunk0 * 16]);
  load_lds16(a1, &sA[0][chunk1 * 16]);
  load_lds16(b0, &sB[0][chunk0 * 16]);
  load_lds16(b1, &sB[0][chunk1 * 16]);
  __syncthreads();  // compiler drains vmcnt before s_barrier -> buf0 ready

  int cur = 0;
  const int NK = K_DIM / 64;
  for (int kt = 0; kt < NK; ++kt) {
    if (kt + 1 < NK) {  // issue next k-tile stage; overlaps with compute below
      const int ko = (kt + 1) * 64;
      load_lds16(a0 + ko, &sA[cur ^ 1][chunk0 * 16]);
      load_lds16(a1 + ko, &sA[cur ^ 1][chunk1 * 16]);
      load_lds16(b0 + ko, &sB[cur ^ 1][chunk0 * 16]);
      load_lds16(b1 + ko, &sB[cur ^ 1][chunk1 * 16]);
    }

    v4i af[4], bf[4];
#pragma unroll
    for (int mi = 0; mi < 4; ++mi)
      af[mi] = *reinterpret_cast<const v4i*>(&sA[cur][aoffBase + mi * 16 * 64]);
#pragma unroll
    for (int ni = 0; ni < 4; ++ni)
      bf[ni] = *reinterpret_cast<const v4i*>(&sB[cur][boffBase + ni * 16 * 64]);

#pragma unroll
    for (int mi = 0; mi < 4; ++mi)
#pragma unroll
      for (int ni = 0; ni < 4; ++ni)
        acc[mi][ni] = __builtin_amdgcn_mfma_i32_16x16x64_i8(af[mi], bf[ni], acc[mi][ni], 0, 0, 0);

    __syncthreads();  // drains the kt+1 stage; also guards buffer reuse
    cur ^= 1;
  }

  // epilogue: C/D frag mapping col=lane&15, row=(lane>>4)*4+reg (m89-verified)
  const int row0 = m0 + wr * 64 + kh * 4;
  const int col0 = n0 + wc * 64 + lr;
#pragma unroll
  for (int ni = 0; ni < 4; ++ni) {
    const int col = col0 + ni * 16;
    const float s = scale[col];
#pragma unroll
    for (int mi = 0; mi < 4; ++mi) {
#pragma unroll
      for (int r = 0; r < 4; ++r) {
        const int row = row0 + mi * 16 + r;
        C[(size_t)row * N_DIM + col] = (float)acc[mi][ni][r] * s;
      }
    }
  }
}

// ---------------------------------------------------------------------------
// Fallback if workspace is too small for A8+Bt (correct but slow)
// ---------------------------------------------------------------------------
__global__ __launch_bounds__(256) void gemm_fallback(const int* __restrict__ A,
                                                     const int* __restrict__ B,
                                                     const float* __restrict__ scale,
                                                     float* __restrict__ C) {
  const int col = blockIdx.x * 16 + (threadIdx.x & 15);
  const int row = blockIdx.y * 16 + (threadIdx.x >> 4);
  int acc = 0;
  for (int k = 0; k < K_DIM; k += 4) {
    const int4 a = *reinterpret_cast<const int4*>(&A[(size_t)row * K_DIM + k]);
    acc += a.x * B[(size_t)(k + 0) * N_DIM + col];
    acc += a.y * B[(size_t)(k + 1) * N_DIM + col];
    acc += a.z * B[(size_t)(k + 2) * N_DIM + col];
    acc += a.w * B[(size_t)(k + 3) * N_DIM + col];
  }
  C[(size_t)row * N_DIM + col] = (float)acc * scale[col];
}

extern "C" void kernel_launch(void* const* d_in, const int* in_sizes, int n_in,
                              void* d_out, int out_size, void* d_ws, size_t ws_size,
                              hipStream_t stream) {
  const int* A32 = (const int*)d_in[0];   // int8 values delivered as int32
  const int* B32 = (const int*)d_in[1];
  const float* scale = (const float*)d_in[2];
  float* C = (float*)d_out;

  const size_t btBytes = (size_t)K_DIM * N_DIM;   // 32 MB
  const size_t a8Bytes = (size_t)M_DIM * K_DIM;   // 16 MB
  if (ws_size >= btBytes + a8Bytes) {
    uint8_t* Bt = (uint8_t*)d_ws;
    uint8_t* A8 = (uint8_t*)d_ws + btBytes;
    pack_a_kernel<<<2048, 256, 0, stream>>>(A32, A8);
    pack_bt_kernel<<<dim3(N_DIM / 128, K_DIM / 128), 256, 0, stream>>>(B32, Bt);
    gemm_i8_kernel<<<dim3(N_DIM / 128, M_DIM / 128), 256, 0, stream>>>(
        A8, Bt, scale, C);
  } else {
    gemm_fallback<<<dim3(N_DIM / 16, M_DIM / 16), 256, 0, stream>>>(
        A32, B32, scale, C);
  }
}

// Round 4
// 388.170 us; speedup vs baseline: 1.1210x; 1.1210x over previous
//
#include <hip/hip_runtime.h>
#include <cstdint>
#include <cstddef>

#define M_DIM 4096
#define K_DIM 4096
#define N_DIM 8192
#define NKT (K_DIM / 128)  // 32 K-tiles of BK=128 bytes

typedef int v4i __attribute__((ext_vector_type(4)));

__device__ __forceinline__ void load_lds16(const void* g, void* l) {
  __builtin_amdgcn_global_load_lds(
      (const __attribute__((address_space(1))) void*)g,
      (__attribute__((address_space(3))) void*)l,
      16, 0, 0);
}

#define FENCE() asm volatile("" ::: "memory")
#define BARRIER()                      \
  do {                                 \
    FENCE();                           \
    __builtin_amdgcn_s_barrier();      \
    FENCE();                           \
  } while (0)
#define VMCNT(n) asm volatile("s_waitcnt vmcnt(" #n ")" ::: "memory")

__device__ __forceinline__ uint32_t pack4(int4 v) {
  return ((uint32_t)v.x & 0xFFu) | (((uint32_t)v.y & 0xFFu) << 8) |
         (((uint32_t)v.z & 0xFFu) << 16) | ((uint32_t)v.w << 24);
}

// ---------------------------------------------------------------------------
// A int32 [M][K] -> A8 int8 [M][K].
// ---------------------------------------------------------------------------
__global__ __launch_bounds__(256) void pack_a_kernel(const int* __restrict__ A32,
                                                     uint8_t* __restrict__ A8) {
  const int n16 = (M_DIM * K_DIM) / 16;
  const int stride = gridDim.x * 256;
  for (int i = blockIdx.x * 256 + threadIdx.x; i < n16; i += stride) {
    const int4* src = reinterpret_cast<const int4*>(A32) + (size_t)i * 4;
    int4 o;
    o.x = (int)pack4(src[0]);
    o.y = (int)pack4(src[1]);
    o.z = (int)pack4(src[2]);
    o.w = (int)pack4(src[3]);
    reinterpret_cast<int4*>(A8)[i] = o;
  }
}

// ---------------------------------------------------------------------------
// B int32 [K][N] -> Bt int8 [N][K]. 128x128 tiles through LDS.
// Stage-2 thread remap (kc=(t&7)*16, nb=(t>>3)*4): lanes 0..7 of a wave
// write one complete 128B Bt row -> full-cacheline stores (8x less write
// amplification than the round-2 scatter). LDS reads 4-way (1.58x, minor).
// ---------------------------------------------------------------------------
#define TPITCH 132
__global__ __launch_bounds__(256) void pack_bt_kernel(const int* __restrict__ B32,
                                                      uint8_t* __restrict__ Bt) {
  __shared__ uint8_t tile[128 * TPITCH];
  const int t = threadIdx.x;
  const int n0 = blockIdx.x * 128;
  const int k0 = blockIdx.y * 128;

#pragma unroll
  for (int c = 0; c < 16; ++c) {
    const int chunk = c * 256 + t;  // 0..4095, 4 int32 each
    const int row = chunk >> 5;     // k-row 0..127
    const int nc4 = (chunk & 31);   // n-dword 0..31
    const int4 v = *reinterpret_cast<const int4*>(
        B32 + (size_t)(k0 + row) * N_DIM + n0 + nc4 * 4);
    *reinterpret_cast<uint32_t*>(&tile[row * TPITCH + nc4 * 4]) = pack4(v);
  }
  __syncthreads();

  const int kc = (t & 7) << 4;   // 0..112
  const int nb = (t >> 3) << 2;  // 0..124
  uint32_t dw[16];
#pragma unroll
  for (int j = 0; j < 16; ++j)
    dw[j] = *reinterpret_cast<const uint32_t*>(&tile[(kc + j) * TPITCH + nb]);

#pragma unroll
  for (int np = 0; np < 4; ++np) {
    const uint32_t sel = (uint32_t)np | (((uint32_t)np + 4u) << 8);
    uint32_t o[4];
#pragma unroll
    for (int d = 0; d < 4; ++d) {
      const uint32_t p01 = __builtin_amdgcn_perm(dw[4 * d + 1], dw[4 * d + 0], sel);
      const uint32_t p23 = __builtin_amdgcn_perm(dw[4 * d + 3], dw[4 * d + 2], sel);
      o[d] = __builtin_amdgcn_perm(p23, p01, 0x05040100u);
    }
    const int4 v = make_int4((int)o[0], (int)o[1], (int)o[2], (int)o[3]);
    *reinterpret_cast<int4*>(Bt + (size_t)(n0 + nb + np) * K_DIM + k0 + kc) = v;
  }
}

// ---------------------------------------------------------------------------
// 256x256 8-phase i8 GEMM (T2 swizzle + T3/T4 counted vmcnt + T5 setprio).
// A8 [M][K], Bt [N][K] int8. 512 threads = 8 waves (2m x 4n), per-wave out
// 128x64. BK=128 bytes, mfma_i32_16x16x64_i8, LDS 128 KiB double-buffered.
// Swizzle: 16B slot s = c16 ^ (row&7); staged via inverse-permuted source;
// ds_read_b128 hits the uniform 8-lanes-per-slot bank floor.
// Stage schedule per K-tile t (NEVER skipped; tail indices clamped to keep
// the vmcnt ledger identical on every tile — fixes the tile-31 A-half race):
//   P0: A[t+1]h0   P1: A[t+1]h1   P2: B[t+2]h0   P3: vmcnt(2); B[t+2]h1
// Ledger at P3's vmcnt(2): outstanding = {B[t+1](4), A[t+1](4), B[t+2]h0(2)}
// -> first 8 land = B[t+1]+A[t+1] complete before the next tile reads them.
// ---------------------------------------------------------------------------
__global__ __launch_bounds__(512, 2) void gemm_i8_kernel(
    const uint8_t* __restrict__ A, const uint8_t* __restrict__ Bt,
    const float* __restrict__ scale, float* __restrict__ C) {
  __shared__ uint8_t lds[2][2][2][128 * 128];  // [buf][A/B][half][16KB]

  const int tid = threadIdx.x;
  const int l = tid & 63;
  const int wave = tid >> 6;
  const int wr = wave >> 2;  // m-half 0..1
  const int wc = wave & 3;   // n-quarter 0..3

  // bijective XCD swizzle over 512 blocks (64 per XCD, 2 full tile-rows each)
  int lin = blockIdx.y * (N_DIM / 256) + blockIdx.x;
  lin = (lin & 7) * 64 + (lin >> 3);
  const int bx = lin & 31;
  const int by = lin >> 5;
  const int m0 = by * 256;
  const int n0 = bx * 256;

  // staging geometry: chunk q*512+tid, r=chunk>>3, s=chunk&7, src c16 = s^(r&7)
  const int r0 = tid >> 3;
  const int r1 = (512 + tid) >> 3;
  const int s0 = tid & 7;
  const int c0 = ((s0 ^ (r0 & 7)) << 4);
  const int c1 = ((s0 ^ (r1 & 7)) << 4);
  const uint8_t* Abase = A + (size_t)m0 * K_DIM;
  const uint8_t* Bbase = Bt + (size_t)n0 * K_DIM;

#define STAGE(OP, BASE, BUF, HALF, T)                                                \
  do {                                                                               \
    load_lds16((BASE) + (size_t)((HALF)*128 + r0) * K_DIM + (T)*128 + c0,            \
               &lds[BUF][OP][HALF][tid * 16]);                                       \
    load_lds16((BASE) + (size_t)((HALF)*128 + r1) * K_DIM + (T)*128 + c1,            \
               &lds[BUF][OP][HALF][(512 + tid) * 16]);                               \
  } while (0)

  // ds_read geometry: row = mi*16 + (l&15), c16 = ks*4 + (l>>4), swizzled
  const int rb = (l & 15) * 128;
  const int aswz0 = (((0 * 4 + (l >> 4)) ^ (l & 7)) << 4);
  const int aswz1 = (((1 * 4 + (l >> 4)) ^ (l & 7)) << 4);
  const int brb = ((wc & 1) * 64) * 128;  // wave's n-offset within its B-half

  v4i acc[8][4];
#pragma unroll
  for (int i = 0; i < 8; ++i)
#pragma unroll
    for (int j = 0; j < 4; ++j) acc[i][j] = (v4i){0, 0, 0, 0};

  // prologue: A[0], B[0] -> buf0; B[1] -> buf1
  STAGE(0, Abase, 0, 0, 0);
  STAGE(0, Abase, 0, 1, 0);
  STAGE(1, Bbase, 0, 0, 0);
  STAGE(1, Bbase, 0, 1, 0);
  STAGE(1, Bbase, 1, 0, 1);
  STAGE(1, Bbase, 1, 1, 1);
  VMCNT(4);  // A[0], B[0] landed; B[1] may remain in flight
  BARRIER();

#define MFMA_CLUSTER(MB, NB)                                                        \
  do {                                                                              \
    __builtin_amdgcn_s_setprio(1);                                                  \
    _Pragma("unroll") for (int mi = 0; mi < 4; ++mi)                                \
        _Pragma("unroll") for (int ni = 0; ni < 2; ++ni) {                          \
      acc[(MB)*4 + mi][(NB)*2 + ni] = __builtin_amdgcn_mfma_i32_16x16x64_i8(        \
          aF[mi][0], bF[(NB)*2 + ni][0], acc[(MB)*4 + mi][(NB)*2 + ni], 0, 0, 0);   \
      acc[(MB)*4 + mi][(NB)*2 + ni] = __builtin_amdgcn_mfma_i32_16x16x64_i8(        \
          aF[mi][1], bF[(NB)*2 + ni][1], acc[(MB)*4 + mi][(NB)*2 + ni], 0, 0, 0);   \
    }                                                                               \
    __builtin_amdgcn_s_setprio(0);                                                  \
    __builtin_amdgcn_sched_barrier(0);                                              \
  } while (0)

#define DO_TILE(T, BUF)                                                             \
  do {                                                                              \
    const int TA = ((T) + 1 < NKT) ? (T) + 1 : NKT - 1; /* clamp: keep ledger */    \
    const int TB = ((T) + 2 < NKT) ? (T) + 2 : NKT - 1; /* identical at tail */     \
    const uint8_t* _As = &lds[BUF][0][wr][0];                                       \
    const uint8_t* _Bs = &lds[BUF][1][wc >> 1][0];                                  \
    v4i aF[4][2];                                                                   \
    v4i bF[4][2];                                                                   \
    /* ---- P0: read A mi0-3 + B ni0-1; stage A[TA]h0; MFMA C00 ---- */             \
    _Pragma("unroll") for (int mi = 0; mi < 4; ++mi) {                              \
      aF[mi][0] = *(const v4i*)&_As[mi * 2048 + rb + aswz0];                        \
      aF[mi][1] = *(const v4i*)&_As[mi * 2048 + rb + aswz1];                        \
    }                                                                               \
    _Pragma("unroll") for (int ni = 0; ni < 2; ++ni) {                              \
      bF[ni][0] = *(const v4i*)&_Bs[brb + ni * 2048 + rb + aswz0];                  \
      bF[ni][1] = *(const v4i*)&_Bs[brb + ni * 2048 + rb + aswz1];                  \
    }                                                                               \
    STAGE(0, Abase, (BUF) ^ 1, 0, TA);                                              \
    BARRIER();                                                                      \
    MFMA_CLUSTER(0, 0);                                                             \
    BARRIER();                                                                      \
    /* ---- P1: read B ni2-3; stage A[TA]h1; MFMA C01 ---- */                       \
    _Pragma("unroll") for (int ni = 2; ni < 4; ++ni) {                              \
      bF[ni][0] = *(const v4i*)&_Bs[brb + ni * 2048 + rb + aswz0];                  \
      bF[ni][1] = *(const v4i*)&_Bs[brb + ni * 2048 + rb + aswz1];                  \
    }                                                                               \
    STAGE(0, Abase, (BUF) ^ 1, 1, TA);                                              \
    BARRIER();                                                                      \
    MFMA_CLUSTER(0, 1);                                                             \
    BARRIER();                                                                      \
    /* ---- P2: read A mi4-7; stage B[TB]h0; MFMA C10 ---- */                       \
    _Pragma("unroll") for (int mi = 0; mi < 4; ++mi) {                              \
      aF[mi][0] = *(const v4i*)&_As[(4 + mi) * 2048 + rb + aswz0];                  \
      aF[mi][1] = *(const v4i*)&_As[(4 + mi) * 2048 + rb + aswz1];                  \
    }                                                                               \
    STAGE(1, Bbase, BUF, 0, TB);                                                    \
    BARRIER();                                                                      \
    MFMA_CLUSTER(1, 0);                                                             \
    BARRIER();                                                                      \
    /* ---- P3: vmcnt(2) [lands A[T+1],B[T+1]]; stage B[TB]h1; MFMA C11 ---- */     \
    VMCNT(2);                                                                       \
    STAGE(1, Bbase, BUF, 1, TB);                                                    \
    BARRIER();                                                                      \
    MFMA_CLUSTER(1, 1);                                                             \
    BARRIER();                                                                      \
  } while (0)

  for (int t = 0; t < NKT; t += 2) {
    DO_TILE(t, 0);
    DO_TILE(t + 1, 1);
  }

  // epilogue: frag (mi,ni): row = m0+wr*128+mi*16+(l>>4)*4+r, col = n0+wc*64+ni*16+(l&15)
  const int csub = (l >> 4) * 4;
  const int colb = n0 + wc * 64 + (l & 15);
  float* Cw = C + (size_t)(m0 + wr * 128) * N_DIM + colb;
#pragma unroll
  for (int ni = 0; ni < 4; ++ni) {
    const float s = scale[colb + ni * 16];
#pragma unroll
    for (int mi = 0; mi < 8; ++mi) {
#pragma unroll
      for (int r = 0; r < 4; ++r) {
        Cw[(size_t)(mi * 16 + csub + r) * N_DIM + ni * 16] =
            (float)acc[mi][ni][r] * s;
      }
    }
  }
#undef DO_TILE
#undef MFMA_CLUSTER
#undef STAGE
}

// ---------------------------------------------------------------------------
// Fallback (ws too small) — correct but slow.
// ---------------------------------------------------------------------------
__global__ __launch_bounds__(256) void gemm_fallback(const int* __restrict__ A,
                                                     const int* __restrict__ B,
                                                     const float* __restrict__ scale,
                                                     float* __restrict__ C) {
  const int col = blockIdx.x * 16 + (threadIdx.x & 15);
  const int row = blockIdx.y * 16 + (threadIdx.x >> 4);
  int acc = 0;
  for (int k = 0; k < K_DIM; k += 4) {
    const int4 a = *reinterpret_cast<const int4*>(&A[(size_t)row * K_DIM + k]);
    acc += a.x * B[(size_t)(k + 0) * N_DIM + col];
    acc += a.y * B[(size_t)(k + 1) * N_DIM + col];
    acc += a.z * B[(size_t)(k + 2) * N_DIM + col];
    acc += a.w * B[(size_t)(k + 3) * N_DIM + col];
  }
  C[(size_t)row * N_DIM + col] = (float)acc * scale[col];
}

extern "C" void kernel_launch(void* const* d_in, const int* in_sizes, int n_in,
                              void* d_out, int out_size, void* d_ws, size_t ws_size,
                              hipStream_t stream) {
  const int* A32 = (const int*)d_in[0];
  const int* B32 = (const int*)d_in[1];
  const float* scale = (const float*)d_in[2];
  float* C = (float*)d_out;

  const size_t btBytes = (size_t)K_DIM * N_DIM;  // 32 MB
  const size_t a8Bytes = (size_t)M_DIM * K_DIM;  // 16 MB
  if (ws_size >= btBytes + a8Bytes) {
    uint8_t* Bt = (uint8_t*)d_ws;
    uint8_t* A8 = (uint8_t*)d_ws + btBytes;
    pack_a_kernel<<<2048, 256, 0, stream>>>(A32, A8);
    pack_bt_kernel<<<dim3(N_DIM / 128, K_DIM / 128), 256, 0, stream>>>(B32, Bt);
    gemm_i8_kernel<<<dim3(N_DIM / 256, M_DIM / 256), 512, 0, stream>>>(
        A8, Bt, scale, C);
  } else {
    gemm_fallback<<<dim3(N_DIM / 16, M_DIM / 16), 256, 0, stream>>>(
        A32, B32, scale, C);
  }
}